// Round 1
// 581.797 us; speedup vs baseline: 1.5380x; 1.5380x over previous
//
#include <hip/hip_runtime.h>

#define HW 16384   // h*w = 128*128
#define C  256
#define D  64
#define NB 16

typedef unsigned short u16;
typedef __attribute__((ext_vector_type(4))) float  f32x4;
typedef __attribute__((ext_vector_type(4))) short  s16x4;
typedef __attribute__((ext_vector_type(8))) short  s16x8;   // 8 bf16 = 4 VGPRs (MFMA A/B frag)

__device__ __forceinline__ float fast_exp(float v) {
    return exp2f(v * 1.44269504088896340736f);
}
// bf16 decode is exact (shift); encode is round-to-nearest-even, matching __float2bfloat16.
__device__ __forceinline__ float bf2f(u16 u) {
    return __uint_as_float(((unsigned int)u) << 16);
}
__device__ __forceinline__ u16 f2bf(float f) {
    unsigned int u = __float_as_uint(f);
    unsigned int r = (u + 0x7fffu + ((u >> 16) & 1u)) >> 16;
    return (u16)r;
}

#define MFMA16(a, b, c) __builtin_amdgcn_mfma_f32_16x16x32_bf16((a), (b), (c), 0, 0, 0)

// ---------------------------------------------------------------------------
// K0: fold conv1 into mk (hi/lo bf16 split for fp32-accurate MFMA),
//     conv2+BN into mv (plain bf16).
//   Ath/Atl[d][cp] : bf16 split of sum_c mk_w[d][c]*conv1_w[c][cp]   (64x256)
//   amk[d]         : sum_c mk_w[d][c]*conv1_b[c]                     (fp32)
//   Bmb[o][d]      : bf16( inv[o] * sum_c conv2_w[o][c]*mv_w[c][d] ) (256x64)
//   shift[o]       : beta[o] - mean[o]*inv[o]                        (fp32)
// ---------------------------------------------------------------------------
__global__ void precompute_kernel(const float* __restrict__ conv1_w,
                                  const float* __restrict__ conv1_b,
                                  const float* __restrict__ mk_w,
                                  const float* __restrict__ mv_w,
                                  const float* __restrict__ conv2_w,
                                  const float* __restrict__ gamma,
                                  const float* __restrict__ beta,
                                  const float* __restrict__ mean,
                                  const float* __restrict__ var,
                                  short* __restrict__ Ath,
                                  short* __restrict__ Atl,
                                  float* __restrict__ amk,
                                  short* __restrict__ Bmb,
                                  float* __restrict__ shift)
{
    int gid = blockIdx.x * blockDim.x + threadIdx.x;
    if (gid < C * D) {
        int d = gid >> 8, cp = gid & 255;          // Ath layout [d][cp]
        float s = 0.f;
        for (int c = 0; c < C; ++c) s += mk_w[d * C + c] * conv1_w[c * C + cp];
        u16 h = f2bf(s);
        Ath[gid] = (short)h;
        Atl[gid] = (short)f2bf(s - bf2f(h));
    } else if (gid < 2 * C * D) {
        int g = gid - C * D;
        int o = g >> 6, d = g & 63;                // Bmb layout [o][d]
        float inv = gamma[o] * rsqrtf(var[o] + 1e-5f);
        float s = 0.f;
        for (int c = 0; c < C; ++c) s += conv2_w[o * C + c] * mv_w[c * D + d];
        Bmb[g] = (short)f2bf(s * inv);
    } else if (gid < 2 * C * D + D) {
        int d = gid - 2 * C * D;
        float s = 0.f;
        for (int c = 0; c < C; ++c) s += mk_w[d * C + c] * conv1_b[c];
        amk[d] = s;
    } else if (gid < 2 * C * D + D + C) {
        int o = gid - (2 * C * D + D);
        float inv = gamma[o] * rsqrtf(var[o] + 1e-5f);
        shift[o] = beta[o] - mean[o] * inv;
    }
}

// ---------------------------------------------------------------------------
// K1: logits[b][d][n] = sum_c At[d][c]*x[b][c][n] + amk[d]  via MFMA bf16.
// 3-term hi/lo split (Ah*xh + Al*xh + Ah*xl) keeps fp32-level accuracy, so
// the stored-bf16-logits error is unchanged vs the fp32 baseline.
// Block: 256 thr (4 waves), 64-n tile. Wave w owns d-tile w (16 d) x 64 n.
// x staged 256c x 64n -> LDS [n][c] bf16 hi|lo (transpose via 4x4 packing so
// LDS writes are b64 and global loads stay float4-coalesced).
// ---------------------------------------------------------------------------
#define NT1 64
__global__ __launch_bounds__(256, 2) void logits_kernel(const float* __restrict__ x,
                                                        const short* __restrict__ Ath,
                                                        const short* __restrict__ Atl,
                                                        const float* __restrict__ amk,
                                                        u16* __restrict__ logits)
{
    __shared__ short xs[NT1][2 * C + 8];   // [n][hi 0..255 | lo 256..511 | pad] = 66.5 KB
    const int t = threadIdx.x;
    const int b = blockIdx.y;
    const int n0 = blockIdx.x * NT1;
    const int lane = t & 63, w = t >> 6;
    const int col = lane & 15, g = lane >> 4;

    // A fragments from global (64 KB table, L2-resident).
    // A[m][k]: m = lane&15 (d within tile), k = ks*32 + 8*(lane>>4) + j  (8 contiguous)
    s16x8 Ah[8], Al[8];
    {
        const short* ah = Ath + (size_t)(w * 16 + col) * C + 8 * g;
        const short* al = Atl + (size_t)(w * 16 + col) * C + 8 * g;
        #pragma unroll
        for (int ks = 0; ks < 8; ++ks) {
            Ah[ks] = *(const s16x8*)(ah + ks * 32);
            Al[ks] = *(const s16x8*)(al + ks * 32);
        }
    }

    // Stage x: 4c x 4n cells; 4 coalesced float4 row-loads -> 2 b64 LDS writes/n.
    const float* xb = x + (size_t)b * C * HW + n0;
    #pragma unroll
    for (int i = 0; i < 4; ++i) {
        int cell = i * 256 + t;
        int nq = cell & 15, cq = cell >> 4;
        int c0 = cq * 4, nn = nq * 4;
        const float* gp = xb + (size_t)c0 * HW + nn;
        f32x4 r0 = *(const f32x4*)(gp);
        f32x4 r1 = *(const f32x4*)(gp + HW);
        f32x4 r2 = *(const f32x4*)(gp + 2 * HW);
        f32x4 r3 = *(const f32x4*)(gp + 3 * HW);
        #pragma unroll
        for (int j = 0; j < 4; ++j) {
            float v0 = r0[j], v1 = r1[j], v2 = r2[j], v3 = r3[j];
            u16 h0 = f2bf(v0), h1 = f2bf(v1), h2 = f2bf(v2), h3 = f2bf(v3);
            s16x4 hi = { (short)h0, (short)h1, (short)h2, (short)h3 };
            s16x4 lo = { (short)f2bf(v0 - bf2f(h0)), (short)f2bf(v1 - bf2f(h1)),
                         (short)f2bf(v2 - bf2f(h2)), (short)f2bf(v3 - bf2f(h3)) };
            *(s16x4*)&xs[nn + j][c0]     = hi;
            *(s16x4*)&xs[nn + j][C + c0] = lo;
        }
    }
    __syncthreads();

    // MFMA main loop: per wave 8 ks x 4 nt x 3 mfma = 96 mfma.
    f32x4 zz = {0.f, 0.f, 0.f, 0.f};
    f32x4 acc[4] = { zz, zz, zz, zz };
    #pragma unroll
    for (int ks = 0; ks < 8; ++ks) {
        #pragma unroll
        for (int nt = 0; nt < 4; ++nt) {
            const short* xr = &xs[nt * 16 + col][ks * 32 + 8 * g];
            s16x8 bh = *(const s16x8*)(xr);
            s16x8 bl = *(const s16x8*)(xr + C);
            acc[nt] = MFMA16(Ah[ks], bh, acc[nt]);
            acc[nt] = MFMA16(Al[ks], bh, acc[nt]);
            acc[nt] = MFMA16(Ah[ks], bl, acc[nt]);
        }
    }

    // Epilogue: + amk, store bf16 logits. D layout: row d = 4*(lane>>4)+r, col n = lane&15.
    f32x4 av = *(const f32x4*)(amk + w * 16 + 4 * g);
    u16* lb = logits + (size_t)b * D * HW + n0;
    #pragma unroll
    for (int nt = 0; nt < 4; ++nt) {
        #pragma unroll
        for (int r = 0; r < 4; ++r) {
            int d = w * 16 + 4 * g + r;
            lb[(size_t)d * HW + nt * 16 + col] = f2bf(acc[nt][r] + av[r]);
        }
    }
}

// ---------------------------------------------------------------------------
// K2: per (b,d) row of 16384 bf16 logits: M = max, invS = 1/sum(exp(l - M)).
// (unchanged from baseline except ushort decode)
// ---------------------------------------------------------------------------
__global__ __launch_bounds__(256) void stats_kernel(const u16* __restrict__ logits,
                                                    float* __restrict__ stats)
{
    const int row = blockIdx.x;               // b*D + d
    const u16* lr = logits + (size_t)row * HW;
    const int t = threadIdx.x;
    const int lane = t & 63, wid = t >> 6;

    float v[64];
    float m = -3.402823466e+38f;
    #pragma unroll
    for (int i = 0; i < 64; ++i) {
        v[i] = bf2f(lr[t + i * 256]);
        m = fmaxf(m, v[i]);
    }
    #pragma unroll
    for (int off = 1; off < 64; off <<= 1) m = fmaxf(m, __shfl_xor(m, off));

    __shared__ float redm[4];
    if (lane == 0) redm[wid] = m;
    __syncthreads();
    const float bm = fmaxf(fmaxf(redm[0], redm[1]), fmaxf(redm[2], redm[3]));

    float s = 0.f;
    #pragma unroll
    for (int i = 0; i < 64; ++i) s += fast_exp(v[i] - bm);
    #pragma unroll
    for (int off = 1; off < 64; off <<= 1) s += __shfl_xor(s, off);

    __shared__ float reds[4];
    if (lane == 0) reds[wid] = s;
    __syncthreads();
    if (t == 0) {
        float S = reds[0] + reds[1] + reds[2] + reds[3];
        stats[2 * row]     = bm;
        stats[2 * row + 1] = 1.0f / S;
    }
}

// ---------------------------------------------------------------------------
// K3: p[d][n] = exp(l-M)*invS (bf16, unnormalized over d);
//     acc[o][n] = MFMA( Bmb[o][d], p[d][n] );  column scale r[n]=1/(1e-9+colsum)
//     applied in epilogue (commutes through the matmul);
//     out = relu(acc*r + shift[o] + x[b][o][n]).
// Block: 512 thr (8 waves), 128-n tile, full 256 o. Wave W: o-block W>>1,
// n-block W&1 -> 64o x 64n per wave (acc 4x4 tiles, K=64 = 2 k-steps).
// ---------------------------------------------------------------------------
#define NT3 128
__global__ __launch_bounds__(512, 4) void out_kernel(const float* __restrict__ x,
                                                     const u16* __restrict__ logits,
                                                     const float* __restrict__ stats,
                                                     const short* __restrict__ Bmb,
                                                     const float* __restrict__ shift,
                                                     float* __restrict__ out)
{
    __shared__ short ps[NT3][72];        // [n][d 0..63 | pad]  18 KB
    __shared__ float csum[4][NT3];       // partial column sums  2 KB
    __shared__ float rr[NT3];            // 1/(1e-9+colsum)      0.5 KB

    const int t = threadIdx.x;
    const int b = blockIdx.y;
    const int n0 = blockIdx.x * NT3;

    // ---- p phase: thread (nl = t&127, dq = t>>7) covers 16 d of column nl ----
    {
        const int nl = t & 127, dq = t >> 7;
        const u16* lg = logits + (size_t)b * D * HW + (size_t)(dq * 16) * HW + n0 + nl;
        const float* st = stats + 2 * (b * D + dq * 16);   // wave-uniform -> scalarized
        float cs = 0.f;
        #pragma unroll
        for (int j4 = 0; j4 < 4; ++j4) {
            s16x4 pk;
            #pragma unroll
            for (int jj = 0; jj < 4; ++jj) {
                int j = j4 * 4 + jj;
                float M = st[2 * j], invS = st[2 * j + 1];
                float pv = fast_exp(bf2f(lg[(size_t)j * HW]) - M) * invS;
                cs += pv;
                pk[jj] = (short)f2bf(pv);
            }
            *(s16x4*)&ps[nl][dq * 16 + j4 * 4] = pk;
        }
        csum[dq][nl] = cs;
    }
    __syncthreads();
    if (t < NT3) {
        float s = csum[0][t] + csum[1][t] + csum[2][t] + csum[3][t] + 1e-9f;
        rr[t] = 1.0f / s;
    }
    __syncthreads();

    const int lane = t & 63, col = lane & 15, g = lane >> 4;
    const int W = t >> 6, Wo = W >> 1, Wn = W & 1;

    // A fragments: Bmb rows o = Wo*64 + ot*16 + (lane&15), k = d (L2-resident 32 KB).
    s16x8 A[4][2];
    #pragma unroll
    for (int ot = 0; ot < 4; ++ot) {
        const short* bp = Bmb + (size_t)(Wo * 64 + ot * 16 + col) * D + 8 * g;
        A[ot][0] = *(const s16x8*)(bp);
        A[ot][1] = *(const s16x8*)(bp + 32);
    }

    f32x4 zz = {0.f, 0.f, 0.f, 0.f};
    f32x4 acc[4][4];                      // [ot][nt]
    #pragma unroll
    for (int ot = 0; ot < 4; ++ot)
        #pragma unroll
        for (int nt = 0; nt < 4; ++nt) acc[ot][nt] = zz;

    #pragma unroll
    for (int nt = 0; nt < 4; ++nt) {
        const short* pr = &ps[Wn * 64 + nt * 16 + col][8 * g];
        s16x8 b0 = *(const s16x8*)(pr);
        s16x8 b1 = *(const s16x8*)(pr + 32);
        #pragma unroll
        for (int ot = 0; ot < 4; ++ot) {
            acc[ot][nt] = MFMA16(A[ot][0], b0, acc[ot][nt]);
            acc[ot][nt] = MFMA16(A[ot][1], b1, acc[ot][nt]);
        }
    }

    // ---- epilogue: *r[n] + shift[o] + x, relu, store ----
    const float* xb = x + (size_t)b * C * HW + n0;
    float* ob = out + (size_t)b * C * HW + n0;
    #pragma unroll
    for (int ot = 0; ot < 4; ++ot) {
        f32x4 sh = *(const f32x4*)(shift + Wo * 64 + ot * 16 + 4 * g);
        #pragma unroll
        for (int nt = 0; nt < 4; ++nt) {
            int nc = Wn * 64 + nt * 16 + col;
            float rv = rr[nc];
            #pragma unroll
            for (int r = 0; r < 4; ++r) {
                int o = Wo * 64 + ot * 16 + 4 * g + r;
                float xv = xb[(size_t)o * HW + nc];
                float v = acc[ot][nt][r] * rv + sh[r] + xv;
                ob[(size_t)o * HW + nc] = fmaxf(v, 0.f);
            }
        }
    }
}

// ---------------------------------------------------------------------------
extern "C" void kernel_launch(void* const* d_in, const int* in_sizes, int n_in,
                              void* d_out, int out_size, void* d_ws, size_t ws_size,
                              hipStream_t stream)
{
    const float* x       = (const float*)d_in[0];
    const float* conv1_w = (const float*)d_in[1];
    const float* conv1_b = (const float*)d_in[2];
    const float* mk_w    = (const float*)d_in[3];
    const float* mv_w    = (const float*)d_in[4];
    const float* conv2_w = (const float*)d_in[5];
    const float* gamma   = (const float*)d_in[6];
    const float* beta    = (const float*)d_in[7];
    const float* mean    = (const float*)d_in[8];
    const float* var     = (const float*)d_in[9];
    float* out = (float*)d_out;

    // workspace layout (all 16B-aligned): fp32 tables, bf16 tables, bf16 logits
    float* amk   = (float*)d_ws;                       // D floats
    float* shift = amk + D;                            // C floats
    float* stats = shift + C;                          // 2*NB*D floats
    short* Ath   = (short*)(stats + 2 * NB * D);       // C*D bf16
    short* Atl   = Ath + C * D;                        // C*D bf16
    short* Bmb   = Atl + C * D;                        // C*D bf16
    u16* logits  = (u16*)(Bmb + C * D);                // NB*D*HW bf16 (~33.5 MB)

    const int pre_work = 2 * C * D + D + C;
    precompute_kernel<<<(pre_work + 255) / 256, 256, 0, stream>>>(
        conv1_w, conv1_b, mk_w, mv_w, conv2_w, gamma, beta, mean, var,
        Ath, Atl, amk, Bmb, shift);

    logits_kernel<<<dim3(HW / NT1, NB), 256, 0, stream>>>(x, Ath, Atl, amk, logits);

    stats_kernel<<<NB * D, 256, 0, stream>>>(logits, stats);

    out_kernel<<<dim3(HW / NT3, NB), 512, 0, stream>>>(x, logits, stats, Bmb, shift, out);
}